// Round 6
// baseline (278.928 us; speedup 1.0000x reference)
//
#include <hip/hip_runtime.h>

typedef unsigned short u16;
typedef __bf16 bf16x8 __attribute__((ext_vector_type(8)));
typedef float f32x4 __attribute__((ext_vector_type(4)));

// ---------- bf16 <-> f32 helpers (RNE) ----------
__device__ __forceinline__ u16 f2bf(float f) {
    union { float f; unsigned int u; } v; v.f = f;
    unsigned int u = v.u;
    return (u16)((u + 0x7FFFu + ((u >> 16) & 1u)) >> 16);
}

// ---------- async global->LDS, 16B per lane ----------
__device__ __forceinline__ void load_lds16(const void* g, void* l) {
    __builtin_amdgcn_global_load_lds(
        (const __attribute__((address_space(1))) unsigned int*)g,
        (__attribute__((address_space(3))) unsigned int*)l,
        16, 0, 0);
}

// ---------------------------------------------------------------
// fused prep: 0..8191 cast x fp32->bf16; 8192..11263 transpose W;
// 11264..11295 zero rowsum (8192 floats).
// ---------------------------------------------------------------
__global__ void __launch_bounds__(256) prep_kernel(
    const float4* __restrict__ X, u16* __restrict__ xb,
    const float* __restrict__ Wq, const float* __restrict__ Wk,
    const float* __restrict__ Wv,
    u16* __restrict__ Oq, u16* __restrict__ Ok, u16* __restrict__ Ov,
    float* __restrict__ rowsum) {
    __shared__ float tile[32][33];
    const int bid = blockIdx.x, tid = threadIdx.x;
    if (bid < 8192) {
        int idx = bid * 256 + tid;
        float4 v = X[idx];
        ushort4 o;
        o.x = f2bf(v.x); o.y = f2bf(v.y); o.z = f2bf(v.z); o.w = f2bf(v.w);
        *(ushort4*)(xb + (size_t)idx * 4) = o;
    } else if (bid < 11264) {
        int id = bid - 8192;
        int zz = id >> 10;
        const float* W = (zz == 0) ? Wq : (zz == 1) ? Wk : Wv;
        u16* O = (zz == 0) ? Oq : (zz == 1) ? Ok : Ov;
        int n0 = (id & 31) * 32, k0 = ((id >> 5) & 31) * 32;
        int tx = tid & 31, ty = tid >> 5;
        #pragma unroll
        for (int j = 0; j < 32; j += 8)
            tile[ty + j][tx] = W[(size_t)(k0 + ty + j) * 1024 + n0 + tx];
        __syncthreads();
        #pragma unroll
        for (int j = 0; j < 32; j += 8)
            O[(size_t)(n0 + ty + j) * 1024 + k0 + tx] = f2bf(tile[tx][ty + j]);
    } else {
        rowsum[(bid - 11264) * 256 + tid] = 0.f;
    }
}

// ---------------------------------------------------------------
// NT bf16 GEMM, 128x128 tile, BK=32 DOUBLE-BUFFERED LDS (32 KiB total):
// prefetch for kiter k+1 is issued BEFORE computing kiter k, so the
// single per-kiter barrier's vmcnt(0) drain has a full compute-phase of
// slack. XOR-swizzled chunks -> conflict-free ds_read_b128. XCD-
// clustered decodes (blocks sharing the reused operand share linear&7).
//
// MODE 0: QKV projections (1536 blocks; z=0/1 -> Q/K row-major, z=2 ->
//         Vt[b][d][s] store).
// MODE 1: P~ = exp(QK^T/32 - 12) into S, live causal tiles only,
//         per-row sums via shfl+atomicAdd (768 blocks).
// MODE 2: O = (P~ V)/rowsum; Vt XCD-local (cluster by ntile); K-loop
//         causally clipped; heavy mtiles first (512 blocks).
// ---------------------------------------------------------------
template <int MODE>
__global__ void __launch_bounds__(256) gemm_nt(
    const u16* __restrict__ xb, const u16* __restrict__ WqT,
    const u16* __restrict__ WkT, const u16* __restrict__ WvT,
    u16* __restrict__ Q, u16* __restrict__ Kb,
    u16* __restrict__ Vt, u16* __restrict__ S,
    float* __restrict__ rowsum, float* __restrict__ out) {

    int mtile, ntile, z;
    const u16 *A, *B;

    if (MODE == 0) {
        int L = blockIdx.x;                       // 1536 blocks
        int c = L & 7, t = (L >> 3) & 7, hi = L >> 6;
        int p = hi * 8 + c;                       // 0..191; mtile&7 == c
        z = p >> 6; mtile = p & 63; ntile = t;
        A = xb;
        B = (z == 0) ? WqT : (z == 1) ? WkT : WvT;
    } else if (MODE == 1) {
        int id2 = blockIdx.x;                     // 768 blocks
        z = id2 / 192;
        int r = id2 - z * 192;
        int c = r & 7, g = r >> 3;
        if (g <= c)            { mtile = c;     ntile = g; }
        else if (g < 2*c + 10) { mtile = c + 8; ntile = g - (c + 1); }
        else return;
        A = Q  + (size_t)z * (2048 * 1024);
        B = Kb + (size_t)z * (2048 * 1024);
    } else {
        int L = blockIdx.x;                       // 512 blocks
        ntile = L & 7;                            // Vt XCD-local
        int j = L >> 3;
        z = j & 3; mtile = 15 - (j >> 2);         // heavy-first
        A = S  + (size_t)z * (2048 * 2048);
        B = Vt + (size_t)z * (1024 * 2048);
    }

    const int LDA = (MODE == 2) ? 2048 : 1024;
    const int kiters = (MODE == 2) ? (mtile + 1) * 4 : 32;   // BK=32

    __shared__ __align__(16) u16 As[2][128 * 32];   // 8 KiB per buffer
    __shared__ __align__(16) u16 Bs[2][128 * 32];

    const int tid = threadIdx.x;
    const int lane = tid & 63;
    const int wave = tid >> 6;
    const int wr = wave >> 1, wc = wave & 1;

    const int r0 = tid >> 2;
    const int kb = (((tid & 3) ^ ((r0 >> 1) & 3))) * 16;   // swizzled 16B chunk

    const char* gA0 = (const char*)(A + (size_t)(mtile * 128 + r0) * LDA) + kb;
    const char* gA1 = gA0 + (size_t)64 * LDA * 2;
    const char* gB0 = (const char*)(B + (size_t)(ntile * 128 + r0) * LDA) + kb;
    const char* gB1 = gB0 + (size_t)64 * LDA * 2;

    char* lA = (char*)(&As[0][0]) + tid * 16;   // buf b at +b*8192; rows 64.. at +4096
    char* lB = (char*)(&Bs[0][0]) + tid * 16;

    f32x4 acc[4][4] = {};

    const int quad = lane >> 4;
    const int l16 = lane & 15;
    const int ch = quad ^ ((l16 >> 1) & 3);     // de-swizzle on read
    const int aoff = (wr * 64 + l16) * 32 + ch * 8;
    const int boff = (wc * 64 + l16) * 32 + ch * 8;

#define STAGE(b) do {                                   \
        load_lds16(gA0, lA + (b) * 8192);               \
        load_lds16(gA1, lA + (b) * 8192 + 4096);        \
        load_lds16(gB0, lB + (b) * 8192);               \
        load_lds16(gB1, lB + (b) * 8192 + 4096);        \
        gA0 += 64; gA1 += 64; gB0 += 64; gB1 += 64;     \
    } while (0)

#define COMPUTE(b) do {                                                       \
        const u16* ap = &As[b][aoff];                                         \
        const u16* bp = &Bs[b][boff];                                         \
        bf16x8 af[4], bfv[4];                                                 \
        _Pragma("unroll")                                                     \
        for (int r = 0; r < 4; ++r) af[r] = *(const bf16x8*)(ap + r * 512);   \
        _Pragma("unroll")                                                     \
        for (int c = 0; c < 4; ++c) bfv[c] = *(const bf16x8*)(bp + c * 512);  \
        _Pragma("unroll")                                                     \
        for (int r = 0; r < 4; ++r)                                           \
            _Pragma("unroll")                                                 \
            for (int c = 0; c < 4; ++c)                                       \
                acc[r][c] = __builtin_amdgcn_mfma_f32_16x16x32_bf16(          \
                    af[r], bfv[c], acc[r][c], 0, 0, 0);                       \
    } while (0)

    STAGE(0);
    __syncthreads();                 // only cold drain (no slack) once
    for (int kt = 0; kt < kiters; kt += 2) {   // kiters is always even
        STAGE(1);                    // prefetch k+1: in flight during COMPUTE(0)
        COMPUTE(0);
        __syncthreads();             // drain has ~compute-phase of slack
        if (kt + 2 < kiters) STAGE(0);
        COMPUTE(1);
        __syncthreads();
    }
#undef STAGE
#undef COMPUTE

    // epilogue — C/D layout: col = lane&15, row = (lane>>4)*4 + reg
    const int grow0 = mtile * 128 + wr * 64 + quad * 4;
    const int gcol0 = ntile * 128 + wc * 64 + l16;

    if (MODE == 0) {
        if (z < 2) {
            u16* C = z ? Kb : Q;
            #pragma unroll
            for (int r = 0; r < 4; ++r)
                #pragma unroll
                for (int c = 0; c < 4; ++c)
                    #pragma unroll
                    for (int i = 0; i < 4; ++i)
                        C[(size_t)(grow0 + r * 16 + i) * 1024 + gcol0 + c * 16] =
                            f2bf(acc[r][c][i]);
        } else {
            // Vt[b][d][s]: m -> (b,s), n -> d; 4 consecutive i -> consecutive s
            #pragma unroll
            for (int r = 0; r < 4; ++r) {
                int m0 = grow0 + r * 16;
                int b = m0 >> 11, s0 = m0 & 2047;
                #pragma unroll
                for (int c = 0; c < 4; ++c) {
                    int d = gcol0 + c * 16;
                    ushort4 o;
                    o.x = f2bf(acc[r][c][0]); o.y = f2bf(acc[r][c][1]);
                    o.z = f2bf(acc[r][c][2]); o.w = f2bf(acc[r][c][3]);
                    *(ushort4*)(Vt + (size_t)b * (1024 * 2048) + (size_t)d * 2048 + s0) = o;
                }
            }
        }
    } else if (MODE == 1) {
        u16* C = S + (size_t)z * (2048 * 2048);
        float* rs = rowsum + z * 2048;
        const bool diag = (ntile == mtile);
        float rsum[4][4];
        #pragma unroll
        for (int r = 0; r < 4; ++r)
            #pragma unroll
            for (int i = 0; i < 4; ++i) rsum[r][i] = 0.f;
        #pragma unroll
        for (int r = 0; r < 4; ++r)
            #pragma unroll
            for (int c = 0; c < 4; ++c)
                #pragma unroll
                for (int i = 0; i < 4; ++i) {
                    int grow = grow0 + r * 16 + i;
                    int gcol = gcol0 + c * 16;
                    float e = 0.f;
                    if (!diag || gcol <= grow)
                        e = __expf(acc[r][c][i] * 0.03125f - 12.0f);
                    C[(size_t)grow * 2048 + gcol] = f2bf(e);
                    rsum[r][i] += e;
                }
        #pragma unroll
        for (int r = 0; r < 4; ++r)
            #pragma unroll
            for (int i = 0; i < 4; ++i) {
                float s = rsum[r][i];
                s += __shfl_xor(s, 1, 64);
                s += __shfl_xor(s, 2, 64);
                s += __shfl_xor(s, 4, 64);
                s += __shfl_xor(s, 8, 64);
                if (l16 == 0)
                    atomicAdd(&rs[grow0 + r * 16 + i], s);
            }
    } else {  // MODE 2: normalize by row sums
        const float* rs = rowsum + z * 2048;
        float* C = out + (size_t)z * (2048 * 1024);
        #pragma unroll
        for (int r = 0; r < 4; ++r)
            #pragma unroll
            for (int i = 0; i < 4; ++i) {
                int grow = grow0 + r * 16 + i;
                float inv = 1.0f / rs[grow];
                #pragma unroll
                for (int c = 0; c < 4; ++c)
                    C[(size_t)grow * 1024 + gcol0 + c * 16] = acc[r][c][i] * inv;
            }
    }
}

// ---------------------------------------------------------------
// launch
// ---------------------------------------------------------------
extern "C" void kernel_launch(void* const* d_in, const int* in_sizes, int n_in,
                              void* d_out, int out_size, void* d_ws, size_t ws_size,
                              hipStream_t stream) {
    const float* x  = (const float*)d_in[0];
    const float* Wq = (const float*)d_in[1];
    const float* Wk = (const float*)d_in[2];
    const float* Wv = (const float*)d_in[3];
    float* out = (float*)d_out;
    char* ws = (char*)d_ws;
    const size_t Mi = 1u << 20;

    u16* xb  = (u16*)(ws);               // [8192][1024] bf16  16 MiB
    u16* WqT = (u16*)(ws + 16 * Mi);     // [1024][1024] bf16   2 MiB
    u16* WkT = (u16*)(ws + 18 * Mi);
    u16* WvT = (u16*)(ws + 20 * Mi);
    u16* Q   = (u16*)(ws + 22 * Mi);     // [8192][1024] bf16  16 MiB
    u16* Kb  = (u16*)(ws + 38 * Mi);
    u16* Vt  = (u16*)(ws + 54 * Mi);     // [4][1024][2048] bf16 16 MiB
    u16* S   = (u16*)(ws + 70 * Mi);     // [4][2048][2048] bf16 32 MiB (P~)
    float* rowsum = (float*)(ws + 102 * Mi);  // [4][2048] fp32

    // prep: cast x + transpose W + zero rowsum
    prep_kernel<<<11296, 256, 0, stream>>>(
        (const float4*)x, xb, Wq, Wk, Wv, WqT, WkT, WvT, rowsum);

    // QKV projections (z: 0=Q, 1=K, 2=Vt)
    gemm_nt<0><<<1536, 256, 0, stream>>>(xb, WqT, WkT, WvT, Q, Kb, Vt, S, rowsum, out);

    // P~ = exp(QK^T/32 - 12) + rowsum, live causal tiles
    gemm_nt<1><<<768, 256, 0, stream>>>(xb, WqT, WkT, WvT, Q, Kb, Vt, S, rowsum, out);

    // O = (P~ V)/rowsum, Vt XCD-local, heavy tiles first
    gemm_nt<2><<<512, 256, 0, stream>>>(xb, WqT, WkT, WvT, Q, Kb, Vt, S, rowsum, out);
}

// Round 7
// 222.453 us; speedup vs baseline: 1.2539x; 1.2539x over previous
//
#include <hip/hip_runtime.h>

typedef unsigned short u16;
typedef __bf16 bf16x8 __attribute__((ext_vector_type(8)));
typedef float f32x4 __attribute__((ext_vector_type(4)));

// ---------- bf16 <-> f32 helpers (RNE) ----------
__device__ __forceinline__ u16 f2bf(float f) {
    union { float f; unsigned int u; } v; v.f = f;
    unsigned int u = v.u;
    return (u16)((u + 0x7FFFu + ((u >> 16) & 1u)) >> 16);
}

// ---------- async global->LDS, 16B per lane ----------
__device__ __forceinline__ void load_lds16(const void* g, void* l) {
    __builtin_amdgcn_global_load_lds(
        (const __attribute__((address_space(1))) unsigned int*)g,
        (__attribute__((address_space(3))) unsigned int*)l,
        16, 0, 0);
}

// ---------------------------------------------------------------
// fused prep: 0..8191 cast x fp32->bf16; 8192..11263 transpose W;
// 11264..11295 zero rowsum (8192 floats).
// ---------------------------------------------------------------
__global__ void __launch_bounds__(256) prep_kernel(
    const float4* __restrict__ X, u16* __restrict__ xb,
    const float* __restrict__ Wq, const float* __restrict__ Wk,
    const float* __restrict__ Wv,
    u16* __restrict__ Oq, u16* __restrict__ Ok, u16* __restrict__ Ov,
    float* __restrict__ rowsum) {
    __shared__ float tile[32][33];
    const int bid = blockIdx.x, tid = threadIdx.x;
    if (bid < 8192) {
        int idx = bid * 256 + tid;
        float4 v = X[idx];
        ushort4 o;
        o.x = f2bf(v.x); o.y = f2bf(v.y); o.z = f2bf(v.z); o.w = f2bf(v.w);
        *(ushort4*)(xb + (size_t)idx * 4) = o;
    } else if (bid < 11264) {
        int id = bid - 8192;
        int zz = id >> 10;
        const float* W = (zz == 0) ? Wq : (zz == 1) ? Wk : Wv;
        u16* O = (zz == 0) ? Oq : (zz == 1) ? Ok : Ov;
        int n0 = (id & 31) * 32, k0 = ((id >> 5) & 31) * 32;
        int tx = tid & 31, ty = tid >> 5;
        #pragma unroll
        for (int j = 0; j < 32; j += 8)
            tile[ty + j][tx] = W[(size_t)(k0 + ty + j) * 1024 + n0 + tx];
        __syncthreads();
        #pragma unroll
        for (int j = 0; j < 32; j += 8)
            O[(size_t)(n0 + ty + j) * 1024 + k0 + tx] = f2bf(tile[tx][ty + j]);
    } else {
        rowsum[(bid - 11264) * 256 + tid] = 0.f;
    }
}

// ---------------------------------------------------------------
// NT bf16 GEMM, 128x128 tile, 512 threads = 8 waves in a 2x4 grid,
// each wave computes 64x32 (acc = 8 f32x4 -> low VGPR -> ~3 blocks/CU
// residency, the latency-hiding we were missing). BK=64 single-buffer
// LDS (32 KiB), stage-all -> barrier -> 32 MFMAs -> barrier (R3-proven).
// XOR-swizzled chunks: conflict-free. XCD-clustered decodes.
//
// MODE 0: QKV projections (1536 blocks; z=0/1 -> Q/K, z=2 -> Vt[b][d][s]).
// MODE 1: P~ = exp(QK^T/32 - 12) into S, live causal tiles, rowsum
//         via shfl+atomicAdd (768 blocks).
// MODE 2: O = (P~ V)/rowsum; Vt XCD-local; K-clipped; heavy-first (512).
// ---------------------------------------------------------------
template <int MODE>
__global__ void __launch_bounds__(512) gemm_nt(
    const u16* __restrict__ xb, const u16* __restrict__ WqT,
    const u16* __restrict__ WkT, const u16* __restrict__ WvT,
    u16* __restrict__ Q, u16* __restrict__ Kb,
    u16* __restrict__ Vt, u16* __restrict__ S,
    float* __restrict__ rowsum, float* __restrict__ out) {

    int mtile, ntile, z;
    const u16 *A, *B;

    if (MODE == 0) {
        int L = blockIdx.x;                       // 1536 blocks
        int c = L & 7, t = (L >> 3) & 7, hi = L >> 6;
        int p = hi * 8 + c;                       // 0..191; mtile&7 == c
        z = p >> 6; mtile = p & 63; ntile = t;
        A = xb;
        B = (z == 0) ? WqT : (z == 1) ? WkT : WvT;
    } else if (MODE == 1) {
        int id2 = blockIdx.x;                     // 768 blocks
        z = id2 / 192;
        int r = id2 - z * 192;
        int c = r & 7, g = r >> 3;
        if (g <= c)            { mtile = c;     ntile = g; }
        else if (g < 2*c + 10) { mtile = c + 8; ntile = g - (c + 1); }
        else return;
        A = Q  + (size_t)z * (2048 * 1024);
        B = Kb + (size_t)z * (2048 * 1024);
    } else {
        int L = blockIdx.x;                       // 512 blocks
        ntile = L & 7;                            // Vt XCD-local
        int j = L >> 3;
        z = j & 3; mtile = 15 - (j >> 2);         // heavy-first
        A = S  + (size_t)z * (2048 * 2048);
        B = Vt + (size_t)z * (1024 * 2048);
    }

    const int LDA = (MODE == 2) ? 2048 : 1024;
    const int kiters = (MODE == 2) ? (mtile + 1) * 2 : 16;   // BK=64

    __shared__ __align__(16) u16 As[128 * 64];   // 16 KiB (two 32-K halves)
    __shared__ __align__(16) u16 Bs[128 * 64];

    const int tid = threadIdx.x;
    const int lane = tid & 63;
    const int wave = tid >> 6;                   // 0..7
    const int wr = wave >> 2, wc = wave & 3;     // 2 x 4 wave grid

    // staging: 512 lanes cover 128 rows x 4 chunks of 16B per half
    const int r0 = tid >> 2;                     // 0..127
    const int kb = (((tid & 3) ^ ((r0 >> 1) & 3))) * 16;   // swizzled chunk

    const char* gA = (const char*)(A + (size_t)(mtile * 128 + r0) * LDA) + kb;
    const char* gB = (const char*)(B + (size_t)(ntile * 128 + r0) * LDA) + kb;

    char* lA = (char*)As + tid * 16;             // half 1 at +8192 B
    char* lB = (char*)Bs + tid * 16;

    f32x4 acc[4][2] = {};

    const int quad = lane >> 4;
    const int l16 = lane & 15;
    const int ch = quad ^ ((l16 >> 1) & 3);      // de-swizzle on read
    const int aoff = (wr * 64 + l16) * 32 + ch * 8;
    const int boff = (wc * 32 + l16) * 32 + ch * 8;

    for (int kt = 0; kt < kiters; ++kt) {
        load_lds16(gA,      lA);
        load_lds16(gA + 64, lA + 8192);
        load_lds16(gB,      lB);
        load_lds16(gB + 64, lB + 8192);
        gA += 128; gB += 128;
        __syncthreads();

        #pragma unroll
        for (int h = 0; h < 2; ++h) {
            const u16* ap = As + h * 4096 + aoff;
            const u16* bp = Bs + h * 4096 + boff;
            bf16x8 af[4], bfv[2];
            #pragma unroll
            for (int r = 0; r < 4; ++r) af[r] = *(const bf16x8*)(ap + r * 512);
            #pragma unroll
            for (int c = 0; c < 2; ++c) bfv[c] = *(const bf16x8*)(bp + c * 512);
            #pragma unroll
            for (int r = 0; r < 4; ++r)
                #pragma unroll
                for (int c = 0; c < 2; ++c)
                    acc[r][c] = __builtin_amdgcn_mfma_f32_16x16x32_bf16(
                        af[r], bfv[c], acc[r][c], 0, 0, 0);
        }
        __syncthreads();
    }

    // epilogue — C/D layout: col = lane&15, row = (lane>>4)*4 + reg
    const int grow0 = mtile * 128 + wr * 64 + quad * 4;
    const int gcol0 = ntile * 128 + wc * 32 + l16;

    if (MODE == 0) {
        if (z < 2) {
            u16* C = z ? Kb : Q;
            #pragma unroll
            for (int r = 0; r < 4; ++r)
                #pragma unroll
                for (int c = 0; c < 2; ++c)
                    #pragma unroll
                    for (int i = 0; i < 4; ++i)
                        C[(size_t)(grow0 + r * 16 + i) * 1024 + gcol0 + c * 16] =
                            f2bf(acc[r][c][i]);
        } else {
            // Vt[b][d][s]: m -> (b,s), n -> d; 4 consecutive i -> consecutive s
            #pragma unroll
            for (int r = 0; r < 4; ++r) {
                int m0 = grow0 + r * 16;
                int b = m0 >> 11, s0 = m0 & 2047;
                #pragma unroll
                for (int c = 0; c < 2; ++c) {
                    int d = gcol0 + c * 16;
                    ushort4 o;
                    o.x = f2bf(acc[r][c][0]); o.y = f2bf(acc[r][c][1]);
                    o.z = f2bf(acc[r][c][2]); o.w = f2bf(acc[r][c][3]);
                    *(ushort4*)(Vt + (size_t)b * (1024 * 2048) + (size_t)d * 2048 + s0) = o;
                }
            }
        }
    } else if (MODE == 1) {
        u16* C = S + (size_t)z * (2048 * 2048);
        float* rs = rowsum + z * 2048;
        const bool diag = (ntile == mtile);
        float rsum[4][4];
        #pragma unroll
        for (int r = 0; r < 4; ++r)
            #pragma unroll
            for (int i = 0; i < 4; ++i) rsum[r][i] = 0.f;
        #pragma unroll
        for (int r = 0; r < 4; ++r)
            #pragma unroll
            for (int c = 0; c < 2; ++c)
                #pragma unroll
                for (int i = 0; i < 4; ++i) {
                    int grow = grow0 + r * 16 + i;
                    int gcol = gcol0 + c * 16;
                    float e = 0.f;
                    if (!diag || gcol <= grow)
                        e = __expf(acc[r][c][i] * 0.03125f - 12.0f);
                    C[(size_t)grow * 2048 + gcol] = f2bf(e);
                    rsum[r][i] += e;
                }
        #pragma unroll
        for (int r = 0; r < 4; ++r)
            #pragma unroll
            for (int i = 0; i < 4; ++i) {
                float s = rsum[r][i];
                s += __shfl_xor(s, 1, 64);
                s += __shfl_xor(s, 2, 64);
                s += __shfl_xor(s, 4, 64);
                s += __shfl_xor(s, 8, 64);
                if (l16 == 0)
                    atomicAdd(&rs[grow0 + r * 16 + i], s);
            }
    } else {  // MODE 2: normalize by row sums
        const float* rs = rowsum + z * 2048;
        float* C = out + (size_t)z * (2048 * 1024);
        #pragma unroll
        for (int r = 0; r < 4; ++r)
            #pragma unroll
            for (int i = 0; i < 4; ++i) {
                int grow = grow0 + r * 16 + i;
                float inv = 1.0f / rs[grow];
                #pragma unroll
                for (int c = 0; c < 2; ++c)
                    C[(size_t)grow * 1024 + gcol0 + c * 16] = acc[r][c][i] * inv;
            }
    }
}

// ---------------------------------------------------------------
// launch
// ---------------------------------------------------------------
extern "C" void kernel_launch(void* const* d_in, const int* in_sizes, int n_in,
                              void* d_out, int out_size, void* d_ws, size_t ws_size,
                              hipStream_t stream) {
    const float* x  = (const float*)d_in[0];
    const float* Wq = (const float*)d_in[1];
    const float* Wk = (const float*)d_in[2];
    const float* Wv = (const float*)d_in[3];
    float* out = (float*)d_out;
    char* ws = (char*)d_ws;
    const size_t Mi = 1u << 20;

    u16* xb  = (u16*)(ws);               // [8192][1024] bf16  16 MiB
    u16* WqT = (u16*)(ws + 16 * Mi);     // [1024][1024] bf16   2 MiB
    u16* WkT = (u16*)(ws + 18 * Mi);
    u16* WvT = (u16*)(ws + 20 * Mi);
    u16* Q   = (u16*)(ws + 22 * Mi);     // [8192][1024] bf16  16 MiB
    u16* Kb  = (u16*)(ws + 38 * Mi);
    u16* Vt  = (u16*)(ws + 54 * Mi);     // [4][1024][2048] bf16 16 MiB
    u16* S   = (u16*)(ws + 70 * Mi);     // [4][2048][2048] bf16 32 MiB (P~)
    float* rowsum = (float*)(ws + 102 * Mi);  // [4][2048] fp32

    // prep: cast x + transpose W + zero rowsum
    prep_kernel<<<11296, 256, 0, stream>>>(
        (const float4*)x, xb, Wq, Wk, Wv, WqT, WkT, WvT, rowsum);

    // QKV projections (z: 0=Q, 1=K, 2=Vt)
    gemm_nt<0><<<1536, 512, 0, stream>>>(xb, WqT, WkT, WvT, Q, Kb, Vt, S, rowsum, out);

    // P~ = exp(QK^T/32 - 12) + rowsum, live causal tiles
    gemm_nt<1><<<768, 512, 0, stream>>>(xb, WqT, WkT, WvT, Q, Kb, Vt, S, rowsum, out);

    // O = (P~ V)/rowsum, Vt XCD-local, heavy tiles first
    gemm_nt<2><<<512, 512, 0, stream>>>(xb, WqT, WkT, WvT, Q, Kb, Vt, S, rowsum, out);
}